// Round 1
// baseline (1434.058 us; speedup 1.0000x reference)
//
#include <hip/hip_runtime.h>
#include <cstdint>
#include <cstddef>

// ---------------- types ----------------
typedef __attribute__((ext_vector_type(8))) __bf16 bf16x8;   // MFMA A/B frag (4 VGPRs)
typedef __attribute__((ext_vector_type(4))) float  f32x4;    // MFMA C/D frag

__device__ __forceinline__ unsigned short f2bf(float f) {
  unsigned u = __float_as_uint(f);
  u += 0x7FFFu + ((u >> 16) & 1u);   // round-to-nearest-even
  return (unsigned short)(u >> 16);
}

// async global->LDS, 16B per lane; LDS dest is wave-uniform base + lane*16
__device__ __forceinline__ void gl_lds16(const void* g, void* l) {
  __builtin_amdgcn_global_load_lds(
      (const __attribute__((address_space(1))) char*)g,
      (__attribute__((address_space(3))) char*)l, 16, 0, 0);
}

__device__ __forceinline__ float sigm(float x) { return 1.f / (1.f + __expf(-x)); }
__device__ __forceinline__ float ftanh(float x) {
  x = fminf(15.f, fmaxf(-15.f, x));
  float e = __expf(2.f * x);
  return (e - 1.f) / (e + 1.f);
}

// ---------------- sort + meta outputs + gathers (1 block) ----------------
__global__ __launch_bounds__(256) void k_sort(
    const float* __restrict__ img, const int* __restrict__ caps,
    const int* __restrict__ clen,
    float* __restrict__ out_caps, float* __restrict__ out_dl, float* __restrict__ out_si,
    int* __restrict__ ws_caps, int* __restrict__ ws_dl,
    unsigned short* __restrict__ h0, float* __restrict__ cbuf)
{
  __shared__ int len_s[64], si_s[64], dl_s[64];
  const int tid = threadIdx.x;
  if (tid < 64) len_s[tid] = clen[tid];
  __syncthreads();
  if (tid < 64) {
    int li = len_s[tid], r = 0;
    for (int j = 0; j < 64; j++) {
      int lj = len_s[j];
      if (lj > li || (lj == li && j < tid)) r++;   // stable descending rank
    }
    si_s[r] = tid;
    dl_s[r] = li - 1;
  }
  __syncthreads();
  if (tid < 64) {
    out_si[tid] = (float)si_s[tid];
    out_dl[tid] = (float)dl_s[tid];
    ws_dl[tid] = dl_s[tid];
  }
  for (int i = tid; i < 64 * 52; i += 256) {
    int p = i / 52, t = i - p * 52;
    int v = caps[si_s[p] * 52 + t];
    out_caps[i] = (float)v;
    ws_caps[i] = v;
  }
  for (int i = tid; i < 64 * 512; i += 256) {
    int b = i >> 9, k = i & 511;
    h0[i] = f2bf(img[si_s[b] * 512 + k]);
    cbuf[i] = 0.f;
  }
}

// ---------------- fp32 -> bf16 cast (vectorized x4) ----------------
__global__ void k_cast(const float* __restrict__ s, unsigned short* __restrict__ d, int n4) {
  int i = blockIdx.x * blockDim.x + threadIdx.x;
  if (i < n4) {
    float4 v = ((const float4*)s)[i];
    ushort4 o;
    o.x = f2bf(v.x); o.y = f2bf(v.y); o.z = f2bf(v.z); o.w = f2bf(v.w);
    ((ushort4*)d)[i] = o;
  }
}

// ---------------- embedding gather -> bf16 A matrix [3264][512] ----------------
__global__ __launch_bounds__(256) void k_gather(
    const float* __restrict__ embW, const int* __restrict__ ws_caps,
    unsigned short* __restrict__ A)
{
  int m = blockIdx.x;                 // 0..3263, m = b*51 + t
  int b = m / 51, t = m - b * 51;
  int tok = ws_caps[b * 52 + t];
  const float* src = embW + (size_t)tok * 512;
  unsigned short* dst = A + (size_t)m * 512;
  for (int k = threadIdx.x; k < 512; k += 256) dst[k] = f2bf(src[k]);
}

// ---------------- 128x128 MFMA GEMM: C = A(MxK) @ Bt(NxK)^T, K=512 ----------------
// EPI 0: out = acc + bias1[col] + bias2[col]          (Xpre)
// EPI 1: out = (t < dl[b]) ? acc + bias1[col] : 0     (predictions; row = b*51+t)
template <int EPI>
__global__ __launch_bounds__(256) void gemm_bt(
    const unsigned short* __restrict__ A, const unsigned short* __restrict__ Bt,
    float* __restrict__ out, int M, int N,
    const float* __restrict__ bias1, const float* __restrict__ bias2,
    const int* __restrict__ dl)
{
  constexpr int K = 512;
  __shared__ unsigned short smA[128 * 32];   // 8 KB
  __shared__ unsigned short smB[128 * 32];   // 8 KB
  const int mtiles = (M + 127) >> 7;
  const int bm = blockIdx.x % mtiles;        // m-fastest for L2 locality on A
  const int bn = blockIdx.x / mtiles;
  const int wave = threadIdx.x >> 6;
  const int lane = threadIdx.x & 63;
  const int srow = lane >> 2;                // 16 rows per 1KB chunk
  const int sbyte = (lane & 3) * 16;
  const int wr = (wave >> 1) * 64;
  const int wc = (wave & 1) * 64;
  const unsigned short* Ab = A + (size_t)bm * 128 * K;
  const unsigned short* Bb = Bt + (size_t)bn * 128 * K;
  f32x4 acc[4][4] = {};
  for (int k0 = 0; k0 < K; k0 += 32) {
#pragma unroll
    for (int cc = 0; cc < 2; cc++) {
      int chunk = wave * 2 + cc;
      int row = chunk * 16 + srow;
      gl_lds16((const char*)(Ab + (size_t)row * K + k0) + sbyte, (char*)smA + chunk * 1024);
      gl_lds16((const char*)(Bb + (size_t)row * K + k0) + sbyte, (char*)smB + chunk * 1024);
    }
    __syncthreads();
    const int rsel = lane & 15;
    const int ko = (lane >> 4) * 8;
    bf16x8 af[4], bfr[4];
#pragma unroll
    for (int mt = 0; mt < 4; mt++)
      af[mt] = *(const bf16x8*)&smA[(wr + mt * 16 + rsel) * 32 + ko];
#pragma unroll
    for (int nt = 0; nt < 4; nt++)
      bfr[nt] = *(const bf16x8*)&smB[(wc + nt * 16 + rsel) * 32 + ko];
#pragma unroll
    for (int mt = 0; mt < 4; mt++)
#pragma unroll
      for (int nt = 0; nt < 4; nt++)
        acc[mt][nt] = __builtin_amdgcn_mfma_f32_16x16x32_bf16(af[mt], bfr[nt], acc[mt][nt], 0, 0, 0);
    __syncthreads();
  }
  // epilogue: C mapping col=lane&15, row=(lane>>4)*4+reg
#pragma unroll
  for (int mt = 0; mt < 4; mt++) {
#pragma unroll
    for (int nt = 0; nt < 4; nt++) {
      int row0 = bm * 128 + wr + mt * 16 + (lane >> 4) * 4;
      int col = bn * 128 + wc + nt * 16 + (lane & 15);
      float b1 = bias1[col];
#pragma unroll
      for (int r = 0; r < 4; r++) {
        int row = row0 + r;
        if (row < M) {
          float v = acc[mt][nt][r];
          if (EPI == 0) {
            out[(size_t)row * N + col] = v + b1 + bias2[col];
          } else {
            int b = row / 51;
            int t = row - b * 51;
            out[(size_t)row * N + col] = (t < dl[b]) ? (v + b1) : 0.f;
          }
        }
      }
    }
  }
}

// ---------------- fused LSTM step: gates MFMA + elementwise ----------------
// grid = 16 blocks; block g owns h-columns [32g, 32g+32) for ALL 4 gates.
// Wave w computes gate q=w (rows 512w+32g..+32 of W_hh) via 4x2 16x16 tiles.
__global__ __launch_bounds__(256) void lstm_step(
    const unsigned short* __restrict__ h_in,   // [64][512] bf16
    unsigned short* __restrict__ h_out,        // [64][512] bf16
    const unsigned short* __restrict__ Whh,    // [2048][512] bf16
    const float* __restrict__ Xpre,            // [3264][2048]
    float* __restrict__ cst,                   // [64][512] fp32
    unsigned short* __restrict__ Hall,         // [3328][512] bf16
    int t)
{
  __shared__ unsigned short smA[64 * 64];    // 8 KB  (BK=64)
  __shared__ unsigned short smB[128 * 64];   // 16 KB
  __shared__ float smG[4 * 64 * 32];         // 32 KB gate exchange
  const int g = blockIdx.x;
  const int wave = threadIdx.x >> 6;
  const int lane = threadIdx.x & 63;
  const int srow = lane >> 3;                // 8 rows per 1KB chunk (128B rows)
  const int sbyte = (lane & 7) * 16;
  f32x4 acc[4][2] = {};
  for (int k0 = 0; k0 < 512; k0 += 64) {
#pragma unroll
    for (int cc = 0; cc < 2; cc++) {         // A: 8 chunks, wave does 2
      int chunk = wave * 2 + cc;
      int row = chunk * 8 + srow;            // 0..63
      gl_lds16((const char*)(h_in + (size_t)row * 512 + k0) + sbyte, (char*)smA + chunk * 1024);
    }
#pragma unroll
    for (int cc = 0; cc < 4; cc++) {         // B: 16 chunks, wave does 4
      int chunk = wave * 4 + cc;
      int lr = chunk * 8 + srow;             // 0..127 local row
      int q = lr >> 5, jj = lr & 31;
      int grow = q * 512 + g * 32 + jj;
      gl_lds16((const char*)(Whh + (size_t)grow * 512 + k0) + sbyte, (char*)smB + chunk * 1024);
    }
    __syncthreads();
    const int rsel = lane & 15;
    const int ko = (lane >> 4) * 8;
#pragma unroll
    for (int kh = 0; kh < 2; kh++) {
      bf16x8 af[4], bfr[2];
#pragma unroll
      for (int mt = 0; mt < 4; mt++)
        af[mt] = *(const bf16x8*)&smA[(mt * 16 + rsel) * 64 + kh * 32 + ko];
#pragma unroll
      for (int nt = 0; nt < 2; nt++)
        bfr[nt] = *(const bf16x8*)&smB[(wave * 32 + nt * 16 + rsel) * 64 + kh * 32 + ko];
#pragma unroll
      for (int mt = 0; mt < 4; mt++)
#pragma unroll
        for (int nt = 0; nt < 2; nt++)
          acc[mt][nt] = __builtin_amdgcn_mfma_f32_16x16x32_bf16(af[mt], bfr[nt], acc[mt][nt], 0, 0, 0);
    }
    __syncthreads();
  }
  // exchange gates through LDS: smG[q][b][jj]
#pragma unroll
  for (int mt = 0; mt < 4; mt++)
#pragma unroll
    for (int nt = 0; nt < 2; nt++) {
      int brow = mt * 16 + (lane >> 4) * 4;
      int jj = nt * 16 + (lane & 15);
#pragma unroll
      for (int r = 0; r < 4; r++)
        smG[(wave * 64 + brow + r) * 32 + jj] = acc[mt][nt][r];
    }
  __syncthreads();
  // fused LSTM elementwise for the 64x32 (b, hc) pairs this block owns
  for (int p = threadIdx.x; p < 2048; p += 256) {
    int b = p >> 5, jj = p & 31;
    int hc = g * 32 + jj;
    size_t mrow = (size_t)(b * 51 + t) * 2048;
    float iv = smG[(0 * 64 + b) * 32 + jj] + Xpre[mrow + hc];
    float fv = smG[(1 * 64 + b) * 32 + jj] + Xpre[mrow + 512 + hc];
    float gv = smG[(2 * 64 + b) * 32 + jj] + Xpre[mrow + 1024 + hc];
    float ov = smG[(3 * 64 + b) * 32 + jj] + Xpre[mrow + 1536 + hc];
    float ivs = sigm(iv), fvs = sigm(fv), gvt = ftanh(gv), ovs = sigm(ov);
    float cn = fvs * cst[(b << 9) + hc] + ivs * gvt;
    float hn = ovs * ftanh(cn);
    cst[(b << 9) + hc] = cn;
    unsigned short hb = f2bf(hn);
    h_out[(b << 9) + hc] = hb;                       // next step's A operand
    Hall[(size_t)(b * 51 + t) * 512 + hc] = hb;      // row for final projection
  }
}

// ---------------- launch ----------------
extern "C" void kernel_launch(void* const* d_in, const int* in_sizes, int n_in,
                              void* d_out, int out_size, void* d_ws, size_t ws_size,
                              hipStream_t stream)
{
  const float* img  = (const float*)d_in[0];
  const int* caps   = (const int*)d_in[1];
  const int* clen   = (const int*)d_in[2];
  const float* embW = (const float*)d_in[3];
  const float* Wih  = (const float*)d_in[4];
  const float* Whh  = (const float*)d_in[5];
  const float* bih  = (const float*)d_in[6];
  const float* bhh  = (const float*)d_in[7];
  const float* linW = (const float*)d_in[8];
  const float* linb = (const float*)d_in[9];

  float* out_pred = (float*)d_out;                       // [64][51][32000]
  float* out_caps = out_pred + (size_t)64 * 51 * 32000;  // [64][52]
  float* out_dl   = out_caps + 64 * 52;                  // [64]
  float* out_si   = out_dl + 64;                         // [64]

  char* p = (char*)d_ws;
  auto alloc = [&](size_t bytes) {
    char* r = p;
    p += (bytes + 255) & ~(size_t)255;
    return r;
  };
  int* ws_caps = (int*)alloc(64 * 52 * sizeof(int));
  int* ws_dl   = (int*)alloc(64 * sizeof(int));
  unsigned short* A_emb = (unsigned short*)alloc((size_t)3328 * 512 * 2);  // padded M
  unsigned short* WihB  = (unsigned short*)alloc((size_t)2048 * 512 * 2);
  unsigned short* WhhB  = (unsigned short*)alloc((size_t)2048 * 512 * 2);
  unsigned short* linWB = (unsigned short*)alloc((size_t)32000 * 512 * 2);
  float* Xpre = (float*)alloc((size_t)3264 * 2048 * sizeof(float));
  unsigned short* Hall = (unsigned short*)alloc((size_t)3328 * 512 * 2);   // padded M
  unsigned short* hc0  = (unsigned short*)alloc((size_t)64 * 512 * 2);
  unsigned short* hc1  = (unsigned short*)alloc((size_t)64 * 512 * 2);
  float* cst = (float*)alloc((size_t)64 * 512 * sizeof(float));

  k_sort<<<1, 256, 0, stream>>>(img, caps, clen, out_caps, out_dl, out_si,
                                ws_caps, ws_dl, hc0, cst);
  k_cast<<<(2048 * 512 / 4 + 255) / 256, 256, 0, stream>>>(Wih, WihB, 2048 * 512 / 4);
  k_cast<<<(2048 * 512 / 4 + 255) / 256, 256, 0, stream>>>(Whh, WhhB, 2048 * 512 / 4);
  k_cast<<<(32000 * 512 / 4 + 255) / 256, 256, 0, stream>>>(linW, linWB, 32000 * 512 / 4);
  k_gather<<<3264, 256, 0, stream>>>(embW, ws_caps, A_emb);

  // Xpre = emb @ W_ih^T + b_ih + b_hh : M=3264, N=2048
  gemm_bt<0><<<26 * 16, 256, 0, stream>>>(A_emb, WihB, Xpre, 3264, 2048, bih, bhh, nullptr);

  for (int t = 0; t < 51; t++) {
    const unsigned short* hi = (t & 1) ? hc1 : hc0;
    unsigned short* ho = (t & 1) ? hc0 : hc1;
    lstm_step<<<16, 256, 0, stream>>>(hi, ho, WhhB, Xpre, cst, Hall, t);
  }

  // predictions = mask(H @ lin_W^T + lin_b) : M=3264, N=32000
  gemm_bt<1><<<26 * 250, 256, 0, stream>>>(Hall, linWB, out_pred, 3264, 32000, linb, nullptr, ws_dl);
}

// Round 2
// 1256.613 us; speedup vs baseline: 1.1412x; 1.1412x over previous
//
#include <hip/hip_runtime.h>
#include <cstdint>
#include <cstddef>

// ---------------- types ----------------
typedef __attribute__((ext_vector_type(8))) __bf16 bf16x8;   // MFMA A/B frag (4 VGPRs)
typedef __attribute__((ext_vector_type(4))) float  f32x4;    // MFMA C/D frag

__device__ __forceinline__ unsigned short f2bf(float f) {
  unsigned u = __float_as_uint(f);
  u += 0x7FFFu + ((u >> 16) & 1u);   // round-to-nearest-even
  return (unsigned short)(u >> 16);
}

// async global->LDS, 16B per lane; LDS dest is wave-uniform base + lane*16
__device__ __forceinline__ void gl_lds16(const void* g, void* l) {
  __builtin_amdgcn_global_load_lds(
      (const __attribute__((address_space(1))) char*)g,
      (__attribute__((address_space(3))) char*)l, 16, 0, 0);
}

__device__ __forceinline__ float sigm(float x) { return 1.f / (1.f + __expf(-x)); }
__device__ __forceinline__ float ftanh(float x) {
  x = fminf(15.f, fmaxf(-15.f, x));
  float e = __expf(2.f * x);
  return (e - 1.f) / (e + 1.f);
}

// ---------------- sort + meta outputs + gathers (1 block) ----------------
__global__ __launch_bounds__(256) void k_sort(
    const float* __restrict__ img, const int* __restrict__ caps,
    const int* __restrict__ clen,
    float* __restrict__ out_caps, float* __restrict__ out_dl, float* __restrict__ out_si,
    int* __restrict__ ws_caps, int* __restrict__ ws_dl,
    unsigned short* __restrict__ h0, float* __restrict__ cbuf,
    int* __restrict__ bar)
{
  __shared__ int len_s[64], si_s[64], dl_s[64];
  const int tid = threadIdx.x;
  if (tid == 0) bar[0] = 0;          // grid-barrier counter for lstm_persist
  if (tid < 64) len_s[tid] = clen[tid];
  __syncthreads();
  if (tid < 64) {
    int li = len_s[tid], r = 0;
    for (int j = 0; j < 64; j++) {
      int lj = len_s[j];
      if (lj > li || (lj == li && j < tid)) r++;   // stable descending rank
    }
    si_s[r] = tid;
    dl_s[r] = li - 1;
  }
  __syncthreads();
  if (tid < 64) {
    out_si[tid] = (float)si_s[tid];
    out_dl[tid] = (float)dl_s[tid];
    ws_dl[tid] = dl_s[tid];
  }
  for (int i = tid; i < 64 * 52; i += 256) {
    int p = i / 52, t = i - p * 52;
    int v = caps[si_s[p] * 52 + t];
    out_caps[i] = (float)v;
    ws_caps[i] = v;
  }
  for (int i = tid; i < 64 * 512; i += 256) {
    int b = i >> 9, k = i & 511;
    h0[i] = f2bf(img[si_s[b] * 512 + k]);
    cbuf[i] = 0.f;
  }
}

// ---------------- fp32 -> bf16 cast (vectorized x4) ----------------
__global__ void k_cast(const float* __restrict__ s, unsigned short* __restrict__ d, int n4) {
  int i = blockIdx.x * blockDim.x + threadIdx.x;
  if (i < n4) {
    float4 v = ((const float4*)s)[i];
    ushort4 o;
    o.x = f2bf(v.x); o.y = f2bf(v.y); o.z = f2bf(v.z); o.w = f2bf(v.w);
    ((ushort4*)d)[i] = o;
  }
}

// ---------------- embedding gather -> bf16 A matrix [3264][512] ----------------
__global__ __launch_bounds__(256) void k_gather(
    const float* __restrict__ embW, const int* __restrict__ ws_caps,
    unsigned short* __restrict__ A)
{
  int m = blockIdx.x;                 // 0..3263, m = b*51 + t
  int b = m / 51, t = m - b * 51;
  int tok = ws_caps[b * 52 + t];
  const float* src = embW + (size_t)tok * 512;
  unsigned short* dst = A + (size_t)m * 512;
  for (int k = threadIdx.x; k < 512; k += 256) dst[k] = f2bf(src[k]);
}

// ---------------- 128x128 MFMA GEMM, BK=64, XOR-swizzled LDS ----------------
// C = A(MxK) @ Bt(NxK)^T, K=512
// LDS layout: row-major [128][64] shorts (128 B rows); 16-B unit j of row r is
// stored at unit j^(r&7) -> fragment reads are 2-way bank aliased (free).
// Tile order: XCD-swizzled — blockIdx%8 picks an XCD-slice of contiguous tiles
// so each B-tile is fetched ~once per XCD instead of 8x.
// EPI 0: out = acc + bias1[col] + bias2[col]          (Xpre)
// EPI 1: out = (t < dl[b]) ? acc + bias1[col] : 0     (predictions; row = b*51+t)
template <int EPI>
__global__ __launch_bounds__(256) void gemm_bt(
    const unsigned short* __restrict__ A, const unsigned short* __restrict__ Bt,
    float* __restrict__ out, int M, int N,
    const float* __restrict__ bias1, const float* __restrict__ bias2,
    const int* __restrict__ dl, int per_xcd)
{
  constexpr int K = 512;
  constexpr int BK = 64;
  __shared__ unsigned short smA[128 * BK];   // 16 KB
  __shared__ unsigned short smB[128 * BK];   // 16 KB
  const int mtiles = (M + 127) >> 7;
  const int total = mtiles * ((N + 127) >> 7);
  int tile = (blockIdx.x & 7) * per_xcd + (blockIdx.x >> 3);
  if (tile >= total) return;
  const int bm = tile % mtiles;
  const int bn = tile / mtiles;
  const int wave = threadIdx.x >> 6;
  const int lane = threadIdx.x & 63;
  const int crow = lane >> 3;                // row within 8-row 1KB chunk
  const int cu   = lane & 7;                 // 16B unit within 128B row
  const int wr = (wave >> 1) * 64;
  const int wc = (wave & 1) * 64;
  const int rsel = lane & 15;
  const int ko = (lane >> 4) * 8;            // 0,8,16,24
  const unsigned short* Ab = A + (size_t)bm * 128 * K;
  const unsigned short* Bb = Bt + (size_t)bn * 128 * K;
  f32x4 acc[4][4] = {};
  for (int k0 = 0; k0 < K; k0 += BK) {
#pragma unroll
    for (int cc = 0; cc < 4; cc++) {
      int chunk = wave * 4 + cc;
      int row = chunk * 8 + crow;
      int gu = cu ^ (row & 7);               // global 16B-unit (swizzle source)
      gl_lds16(Ab + (size_t)row * K + k0 + gu * 8, (char*)smA + chunk * 1024);
      gl_lds16(Bb + (size_t)row * K + k0 + gu * 8, (char*)smB + chunk * 1024);
    }
    __syncthreads();
    bf16x8 af[2][4], bfr[2][4];
#pragma unroll
    for (int kh = 0; kh < 2; kh++) {
      int u = kh * 4 + (ko >> 3);            // 16B unit index 0..7
#pragma unroll
      for (int mt = 0; mt < 4; mt++) {
        int row = wr + mt * 16 + rsel;
        af[kh][mt] = *(const bf16x8*)&smA[row * BK + ((u ^ (row & 7)) << 3)];
      }
#pragma unroll
      for (int nt = 0; nt < 4; nt++) {
        int row = wc + nt * 16 + rsel;
        bfr[kh][nt] = *(const bf16x8*)&smB[row * BK + ((u ^ (row & 7)) << 3)];
      }
    }
#pragma unroll
    for (int kh = 0; kh < 2; kh++)
#pragma unroll
      for (int mt = 0; mt < 4; mt++)
#pragma unroll
        for (int nt = 0; nt < 4; nt++)
          acc[mt][nt] = __builtin_amdgcn_mfma_f32_16x16x32_bf16(af[kh][mt], bfr[kh][nt], acc[mt][nt], 0, 0, 0);
    __syncthreads();
  }
  // epilogue: C mapping col=lane&15, row=(lane>>4)*4+reg
#pragma unroll
  for (int mt = 0; mt < 4; mt++) {
#pragma unroll
    for (int nt = 0; nt < 4; nt++) {
      int row0 = bm * 128 + wr + mt * 16 + (lane >> 4) * 4;
      int col = bn * 128 + wc + nt * 16 + (lane & 15);
      float b1 = bias1[col];
#pragma unroll
      for (int r = 0; r < 4; r++) {
        int row = row0 + r;
        if (row < M) {
          float v = acc[mt][nt][r];
          if (EPI == 0) {
            out[(size_t)row * N + col] = v + b1 + bias2[col];
          } else {
            int b = row / 51;
            int t = row - b * 51;
            out[(size_t)row * N + col] = (t < dl[b]) ? (v + b1) : 0.f;
          }
        }
      }
    }
  }
}

// ---------------- persistent fused LSTM: all 51 steps in one launch ----------
// grid = 16 blocks; block g owns h-columns [32g, 32g+32) for ALL 4 gates.
// Cross-block h exchange via global + atomic grid barrier (16 blocks are
// trivially co-resident on 256 CUs; __threadfence gives device-scope rel/acq).
__global__ __launch_bounds__(256) void lstm_persist(
    unsigned short* __restrict__ hc0,          // [64][512] bf16 (t even input)
    unsigned short* __restrict__ hc1,          // [64][512] bf16
    const unsigned short* __restrict__ Whh,    // [2048][512] bf16
    const float* __restrict__ Xpre,            // [3264][2048]
    float* __restrict__ cst,                   // [64][512] fp32
    unsigned short* __restrict__ Hall,         // [3328][512] bf16
    int* __restrict__ bar)
{
  __shared__ unsigned short smA[64 * 64];    // 8 KB  (BK=64, swizzled)
  __shared__ unsigned short smB[128 * 64];   // 16 KB (swizzled)
  __shared__ float smG[4 * 64 * 32];         // 32 KB gate exchange
  const int g = blockIdx.x;
  const int wave = threadIdx.x >> 6;
  const int lane = threadIdx.x & 63;
  const int crow = lane >> 3;
  const int cu   = lane & 7;
  const int rsel = lane & 15;
  const int ko = (lane >> 4) * 8;

  for (int t = 0; t < 51; t++) {
    const unsigned short* h_in = (t & 1) ? hc1 : hc0;
    unsigned short* h_out      = (t & 1) ? hc0 : hc1;

    // prefetch this step's Xpre slice into registers (independent of h)
    float xp[8][4];
#pragma unroll
    for (int pi = 0; pi < 8; pi++) {
      int p = pi * 256 + threadIdx.x;        // 0..2047
      int b = p >> 5, jj = p & 31;
      const float* xrow = Xpre + (size_t)(b * 51 + t) * 2048 + g * 32 + jj;
      xp[pi][0] = xrow[0];
      xp[pi][1] = xrow[512];
      xp[pi][2] = xrow[1024];
      xp[pi][3] = xrow[1536];
    }

    f32x4 acc[4][2] = {};
    for (int k0 = 0; k0 < 512; k0 += 64) {
#pragma unroll
      for (int cc = 0; cc < 2; cc++) {       // A: 8 chunks, wave does 2
        int chunk = wave * 2 + cc;
        int row = chunk * 8 + crow;          // 0..63
        int gu = cu ^ (row & 7);
        gl_lds16(h_in + (size_t)row * 512 + k0 + gu * 8, (char*)smA + chunk * 1024);
      }
#pragma unroll
      for (int cc = 0; cc < 4; cc++) {       // B: 16 chunks, wave does 4
        int chunk = wave * 4 + cc;
        int lr = chunk * 8 + crow;           // 0..127 local row
        int q = lr >> 5, jj = lr & 31;
        int grow = q * 512 + g * 32 + jj;
        int gu = cu ^ (lr & 7);
        gl_lds16(Whh + (size_t)grow * 512 + k0 + gu * 8, (char*)smB + chunk * 1024);
      }
      __syncthreads();
#pragma unroll
      for (int kh = 0; kh < 2; kh++) {
        int u = kh * 4 + (ko >> 3);
        bf16x8 af[4], bfr[2];
#pragma unroll
        for (int mt = 0; mt < 4; mt++) {
          int row = mt * 16 + rsel;
          af[mt] = *(const bf16x8*)&smA[row * 64 + ((u ^ (row & 7)) << 3)];
        }
#pragma unroll
        for (int nt = 0; nt < 2; nt++) {
          int row = wave * 32 + nt * 16 + rsel;
          bfr[nt] = *(const bf16x8*)&smB[row * 64 + ((u ^ (row & 7)) << 3)];
        }
#pragma unroll
        for (int mt = 0; mt < 4; mt++)
#pragma unroll
          for (int nt = 0; nt < 2; nt++)
            acc[mt][nt] = __builtin_amdgcn_mfma_f32_16x16x32_bf16(af[mt], bfr[nt], acc[mt][nt], 0, 0, 0);
      }
      __syncthreads();
    }
    // exchange gates through LDS: smG[q][b][jj]; wave w computed gate q=w
#pragma unroll
    for (int mt = 0; mt < 4; mt++)
#pragma unroll
      for (int nt = 0; nt < 2; nt++) {
        int brow = mt * 16 + (lane >> 4) * 4;
        int jj = nt * 16 + (lane & 15);
#pragma unroll
        for (int r = 0; r < 4; r++)
          smG[(wave * 64 + brow + r) * 32 + jj] = acc[mt][nt][r];
      }
    __syncthreads();
    // fused LSTM elementwise for the 64x32 (b, hc) pairs this block owns
#pragma unroll
    for (int pi = 0; pi < 8; pi++) {
      int p = pi * 256 + threadIdx.x;
      int b = p >> 5, jj = p & 31;
      int hc = g * 32 + jj;
      float iv = smG[(0 * 64 + b) * 32 + jj] + xp[pi][0];
      float fv = smG[(1 * 64 + b) * 32 + jj] + xp[pi][1];
      float gv = smG[(2 * 64 + b) * 32 + jj] + xp[pi][2];
      float ov = smG[(3 * 64 + b) * 32 + jj] + xp[pi][3];
      float ivs = sigm(iv), fvs = sigm(fv), gvt = ftanh(gv), ovs = sigm(ov);
      float cn = fvs * cst[(b << 9) + hc] + ivs * gvt;
      float hn = ovs * ftanh(cn);
      cst[(b << 9) + hc] = cn;
      unsigned short hb = f2bf(hn);
      h_out[(b << 9) + hc] = hb;                       // next step's A operand
      Hall[(size_t)(b * 51 + t) * 512 + hc] = hb;      // row for final projection
    }
    // grid barrier (not needed after the last step)
    if (t != 50) {
      __syncthreads();
      if (threadIdx.x == 0) {
        __threadfence();                               // release h_out (L2 wb)
        atomicAdd(bar, 1);
        int goal = 16 * (t + 1);
        while (__hip_atomic_load(bar, __ATOMIC_RELAXED, __HIP_MEMORY_SCOPE_AGENT) < goal)
          __builtin_amdgcn_s_sleep(2);
        __threadfence();                               // acquire (L1/L2 inv)
      }
      __syncthreads();
    }
  }
}

// ---------------- launch ----------------
extern "C" void kernel_launch(void* const* d_in, const int* in_sizes, int n_in,
                              void* d_out, int out_size, void* d_ws, size_t ws_size,
                              hipStream_t stream)
{
  const float* img  = (const float*)d_in[0];
  const int* caps   = (const int*)d_in[1];
  const int* clen   = (const int*)d_in[2];
  const float* embW = (const float*)d_in[3];
  const float* Wih  = (const float*)d_in[4];
  const float* Whh  = (const float*)d_in[5];
  const float* bih  = (const float*)d_in[6];
  const float* bhh  = (const float*)d_in[7];
  const float* linW = (const float*)d_in[8];
  const float* linb = (const float*)d_in[9];

  float* out_pred = (float*)d_out;                       // [64][51][32000]
  float* out_caps = out_pred + (size_t)64 * 51 * 32000;  // [64][52]
  float* out_dl   = out_caps + 64 * 52;                  // [64]
  float* out_si   = out_dl + 64;                         // [64]

  char* p = (char*)d_ws;
  auto alloc = [&](size_t bytes) {
    char* r = p;
    p += (bytes + 255) & ~(size_t)255;
    return r;
  };
  int* ws_caps = (int*)alloc(64 * 52 * sizeof(int));
  int* ws_dl   = (int*)alloc(64 * sizeof(int));
  int* bar     = (int*)alloc(256);
  unsigned short* A_emb = (unsigned short*)alloc((size_t)3328 * 512 * 2);  // padded M
  unsigned short* WihB  = (unsigned short*)alloc((size_t)2048 * 512 * 2);
  unsigned short* WhhB  = (unsigned short*)alloc((size_t)2048 * 512 * 2);
  unsigned short* linWB = (unsigned short*)alloc((size_t)32000 * 512 * 2);
  float* Xpre = (float*)alloc((size_t)3264 * 2048 * sizeof(float));
  unsigned short* Hall = (unsigned short*)alloc((size_t)3328 * 512 * 2);   // padded M
  unsigned short* hc0  = (unsigned short*)alloc((size_t)64 * 512 * 2);
  unsigned short* hc1  = (unsigned short*)alloc((size_t)64 * 512 * 2);
  float* cst = (float*)alloc((size_t)64 * 512 * sizeof(float));

  k_sort<<<1, 256, 0, stream>>>(img, caps, clen, out_caps, out_dl, out_si,
                                ws_caps, ws_dl, hc0, cst, bar);
  k_cast<<<(2048 * 512 / 4 + 255) / 256, 256, 0, stream>>>(Wih, WihB, 2048 * 512 / 4);
  k_cast<<<(2048 * 512 / 4 + 255) / 256, 256, 0, stream>>>(Whh, WhhB, 2048 * 512 / 4);
  k_cast<<<(32000 * 512 / 4 + 255) / 256, 256, 0, stream>>>(linW, linWB, 32000 * 512 / 4);
  k_gather<<<3264, 256, 0, stream>>>(embW, ws_caps, A_emb);

  // Xpre = emb @ W_ih^T + b_ih + b_hh : M=3264, N=2048 -> 26x16 = 416 tiles
  {
    int total = 26 * 16, per = (total + 7) / 8;
    gemm_bt<0><<<per * 8, 256, 0, stream>>>(A_emb, WihB, Xpre, 3264, 2048, bih, bhh, nullptr, per);
  }

  // all 51 recurrent steps in one persistent launch
  lstm_persist<<<16, 256, 0, stream>>>(hc0, hc1, WhhB, Xpre, cst, Hall, bar);

  // predictions = mask(H @ lin_W^T + lin_b) : M=3264, N=32000 -> 26x250 = 6500 tiles
  {
    int total = 26 * 250, per = (total + 7) / 8;   // 813 -> grid 6504
    gemm_bt<1><<<per * 8, 256, 0, stream>>>(Hall, linWB, out_pred, 3264, 32000, linb, nullptr, ws_dl, per);
  }
}